// Round 1
// baseline (109.233 us; speedup 1.0000x reference)
//
#include <hip/hip_runtime.h>
#include <math.h>

#define K_ 32
#define D_ 8
#define NF 48          // 36 quad + 8 lin + 1 const + 3 pad features
#define NTHREADS 256
#define NBLOCKS 1024
#define TPW 4          // tiles per wave, fully unrolled, loads hoisted

typedef _Float16 half8 __attribute__((ext_vector_type(8)));
typedef float f32x16 __attribute__((ext_vector_type(16)));

// ---------------------------------------------------------------------------
// Round-11: split preprocessing out of the hot kernel.
// Previous structure re-ran the K=32 Cholesky-inverse/A2/lse pipeline in a
// divergent half-wave in EVERY block (1024x redundant), with ~240 live floats
// inflating VGPR allocation for the whole kernel (occupancy cap) plus an LDS
// round-trip + __syncthreads. Now a one-wave prep kernel writes the f16
// A-fragment table [3][64][8] (3 KB) to workspace once; the hot kernel loads
// fragments straight from L2, has no LDS/barrier/divergent block, and builds
// B-operand features per-MFMA-block (16 live floats, not 48) to keep
// VGPR <= 128 so __launch_bounds__(256,4) holds 4 waves/SIMD.
//
// Math (unchanged from round-9/10): maha = x^T A x - 2 b^T x + mu^T b with
// A = L^-T L^-1, b = A mu. In log2 domain (alpha = 0.5*log2e):
//   W2[n][k] = sum_f V[k][f] * Y[n][f],  Y = [x_i x_j (j<=i), x_i, 1, pad]
//   out = ln2 * log2(sum_k exp2(W2))  -- W2 in (-80,-3), no max-subtract
// 3x v_mfma_f32_32x32x16_f16 per 32-sample tile; A-op = weights (M=K_),
// B-op = features (N=samples). C-layout: row=k=(reg&3)+8*(reg>>2)+4*(lane>>5),
// col=sample=lane&31 -> k-reduce = 16 exp2 + 15 adds in-lane + 1 shfl_xor(32).
// Grid covers tiles exactly: 1024 blk x 4 waves x 4 tiles = 16384 = N/32.
// ---------------------------------------------------------------------------

__global__ void gmm_prep(
    const float* __restrict__ pi,
    const float* __restrict__ means,
    const float* __restrict__ chol,
    _Float16* __restrict__ wsV)
{
    const int k = threadIdx.x;
    if (k >= K_) return;

    float L[D_][D_];
#pragma unroll
    for (int i = 0; i < D_; ++i)
#pragma unroll
        for (int j = 0; j <= i; ++j)
            L[i][j] = chol[k * 64 + i * 8 + j];

    float rd[D_];
#pragma unroll
    for (int i = 0; i < D_; ++i) rd[i] = 1.f / L[i][i];

    // Ci = L^{-1}; chol(LL^T + eps I) = L*sign, maha/logdet sign-invariant
    float Ci[D_][D_];
#pragma unroll
    for (int j = 0; j < D_; ++j) {
        Ci[j][j] = rd[j];
#pragma unroll
        for (int i = j + 1; i < D_; ++i) {
            float s = 0.f;
#pragma unroll
            for (int m = j; m < i; ++m) s += L[i][m] * Ci[m][j];
            Ci[i][j] = -s * rd[i];
        }
    }

    float logdet = 0.f;
#pragma unroll
    for (int i = 0; i < D_; ++i) logdet += __logf(fabsf(L[i][i]));
    logdet *= 2.f;

    // A2 = Ci^T Ci
    float A2[D_][D_];
#pragma unroll
    for (int i = 0; i < D_; ++i)
#pragma unroll
        for (int j = 0; j <= i; ++j) {
            float s = 0.f;
#pragma unroll
            for (int m = i; m < D_; ++m) s += Ci[m][i] * Ci[m][j];
            A2[i][j] = s;
            A2[j][i] = s;
        }

    float mu[D_];
#pragma unroll
    for (int j = 0; j < D_; ++j) mu[j] = means[k * 8 + j];
    float b[D_], q = 0.f;
#pragma unroll
    for (int i = 0; i < D_; ++i) {
        float s = 0.f;
#pragma unroll
        for (int j = 0; j < D_; ++j) s += A2[i][j] * mu[j];
        b[i] = s;
        q += s * mu[i];
    }

    float mx = pi[0];
#pragma unroll
    for (int t = 1; t < K_; ++t) mx = fmaxf(mx, pi[t]);
    float se = 0.f;
#pragma unroll
    for (int t = 0; t < K_; ++t) se += __expf(pi[t] - mx);
    float lse = mx + __logf(se);

    const float LOG2PI = 1.8378770664093453f;
    const float LOG2E  = 1.4426950408889634f;
    const float ALPHA  = 0.72134752044448170f;  // 0.5 * log2e
    float cst2 = ((pi[k] - lse) - 0.5f * (logdet + 8.f * LOG2PI)) * LOG2E;

    float V[NF];
    int t = 0;
#pragma unroll
    for (int i = 0; i < D_; ++i)
#pragma unroll
        for (int j = 0; j <= i; ++j)
            V[t++] = (i == j) ? -ALPHA * A2[i][i] : -2.f * ALPHA * A2[i][j];
#pragma unroll
    for (int i = 0; i < D_; ++i) V[36 + i] = 2.f * ALPHA * b[i];
    V[44] = cst2 - ALPHA * q;
    V[45] = 0.f; V[46] = 0.f; V[47] = 0.f;

    // fragment layout: lane l of the hot kernel reads wsV[s][l][0..7],
    // l = h*32 + k, feature = 16*s + 8*h + j
#pragma unroll
    for (int s = 0; s < 3; ++s)
#pragma unroll
        for (int h = 0; h < 2; ++h)
#pragma unroll
            for (int j = 0; j < 8; ++j)
                wsV[(s * 64 + h * 32 + k) * 8 + j] = (_Float16)V[16 * s + 8 * h + j];
}

__global__ __launch_bounds__(NTHREADS, 4) void gmm_mfma(
    const float* __restrict__ x,
    const _Float16* __restrict__ wsV,
    float* __restrict__ out)
{
    const int tid  = threadIdx.x;
    const int lane = tid & 63;
    const int m    = lane & 31;
    const bool h1  = lane >= 32;

    const int w  = blockIdx.x * (NTHREADS / 64) + (tid >> 6);
    const int t0 = w * TPW;
    const float4* xp = (const float4*)x;
    const float LN2 = 0.69314718055994531f;

    // ---- all TPW*2 x-loads issued before any compute ----
    float xv[TPW][D_];
#pragma unroll
    for (int u = 0; u < TPW; ++u) {
        const int n = (t0 + u) * 32 + m;
        float4 a = xp[2 * n], b2 = xp[2 * n + 1];
        xv[u][0] = a.x;  xv[u][1] = a.y;  xv[u][2] = a.z;  xv[u][3] = a.w;
        xv[u][4] = b2.x; xv[u][5] = b2.y; xv[u][6] = b2.z; xv[u][7] = b2.w;
    }

    // A-operand fragments from the prep table (3 KB, L2-resident)
    const half8* wp = (const half8*)wsV;
    half8 wf[3];
#pragma unroll
    for (int s = 0; s < 3; ++s) wf[s] = wp[s * 64 + lane];

#pragma unroll
    for (int u = 0; u < TPW; ++u) {
        f32x16 acc;
#pragma unroll
        for (int r = 0; r < 16; ++r) acc[r] = 0.f;

#pragma unroll
        for (int s = 0; s < 3; ++s) {
            // build only this MFMA-block's 16 features (keeps 16 live, not 48)
            float yb[16];
            int t = 0;
#pragma unroll
            for (int i = 0; i < D_; ++i)
#pragma unroll
                for (int j = 0; j <= i; ++j) {
                    if (t >= 16 * s && t < 16 * (s + 1))
                        yb[t - 16 * s] = xv[u][i] * xv[u][j];
                    ++t;
                }
#pragma unroll
            for (int i = 0; i < D_; ++i) {
                const int f = 36 + i;
                if (f >= 16 * s && f < 16 * (s + 1)) yb[f - 16 * s] = xv[u][i];
            }
            if (s == 2) { yb[12] = 1.f; yb[13] = 0.f; yb[14] = 0.f; yb[15] = 0.f; }

            half8 bf;
#pragma unroll
            for (int j = 0; j < 8; ++j) {
                float v = h1 ? yb[8 + j] : yb[j];
                bf[j] = (_Float16)v;
            }
            acc = __builtin_amdgcn_mfma_f32_32x32x16_f16(wf[s], bf, acc, 0, 0, 0);
        }

        float tot = 0.f;
#pragma unroll
        for (int r = 0; r < 16; ++r) tot += exp2f(acc[r]);
        tot += __shfl_xor(tot, 32, 64);
        float res = log2f(tot) * LN2;
        if (!h1) out[(t0 + u) * 32 + m] = res;  // coalesced 128B store
    }
}

extern "C" void kernel_launch(void* const* d_in, const int* in_sizes, int n_in,
                              void* d_out, int out_size, void* d_ws, size_t ws_size,
                              hipStream_t stream) {
    const float* x     = (const float*)d_in[0];
    const float* pi    = (const float*)d_in[1];
    const float* means = (const float*)d_in[2];
    const float* chol  = (const float*)d_in[3];
    float* out = (float*)d_out;
    _Float16* wsV = (_Float16*)d_ws;
    (void)in_sizes; (void)n_in; (void)out_size; (void)ws_size;

    gmm_prep<<<1, 64, 0, stream>>>(pi, means, chol, wsV);
    gmm_mfma<<<NBLOCKS, NTHREADS, 0, stream>>>(x, wsV, out);
}